// Round 13
// baseline (278.408 us; speedup 1.0000x reference)
//
#include <hip/hip_runtime.h>
#include <hip/hip_bf16.h>
#include <stdint.h>

#define T_TOK 2048
#define DIM   1024
#define HDIM  2048
#define NE    8
#define ROWS_PAD 4224   // 4096 routed rows + 128 pad for tile overrun
#define TSLOTS 40       // max live (expert,mtile) pairs: 32 + 7 = 39

typedef __attribute__((ext_vector_type(8))) short bf16x8;
typedef __attribute__((ext_vector_type(8))) unsigned short u16x8;
typedef __attribute__((ext_vector_type(4))) float f32x4;

__device__ __forceinline__ unsigned short f2bf(float f) {
    union { float f; unsigned int u; } v; v.f = f;
    unsigned int r = v.u + 0x7FFF + ((v.u >> 16) & 1);   // round-nearest-even
    return (unsigned short)(r >> 16);
}

__device__ __forceinline__ float bf2f(unsigned short b) {
    union { unsigned int u; float f; } v; v.u = ((unsigned int)b) << 16;
    return v.f;
}

__device__ __forceinline__ void gload16(const void* g, void* l) {
    __builtin_amdgcn_global_load_lds(
        (const __attribute__((address_space(1))) void*)g,
        (__attribute__((address_space(3))) void*)l, 16, 0, 0);
}

// ---------------- prep: fused {gw,uw,dw 512x64-tile transpose+cvt} + router
// Tile: 512 in-rows x 64 in-cols. Reads = 256B row-chunks (coalesced).
// Writes = 1KB contiguous per wave (out-row chunk of 512 bf16).
// blocks [0, 1536): transpose tiles (512 per matrix); [1536, 2048): router.
#define NTT 1536
__global__ __launch_bounds__(256, 2)
void prep_kernel(const float* __restrict__ gw, const float* __restrict__ uw,
                 const float* __restrict__ dw,
                 unsigned short* __restrict__ WgT, unsigned short* __restrict__ WuT,
                 unsigned short* __restrict__ WdT,
                 const float* __restrict__ x, const float* __restrict__ rw,
                 int* __restrict__ counts, int* __restrict__ top_idx,
                 float* __restrict__ top_w) {
    __shared__ __align__(16) unsigned short lt[512][68];   // 69632 B, pad 68
    const int b = blockIdx.x;
    if (b < NTT) {
        const int m = b >> 9;           // 0=gw, 1=uw, 2=dw (512 tiles each)
        const int t = b & 511;
        const int e = t >> 6;           // 64 tiles per expert
        const int rem = t & 63;
        const float* in; unsigned short* out; int Ri, Ci, ri, ci;
        if (m == 0)      { in = gw; out = WgT; Ri = DIM;  Ci = HDIM; ri = rem & 1; ci = rem >> 1; }
        else if (m == 1) { in = uw; out = WuT; Ri = DIM;  Ci = HDIM; ri = rem & 1; ci = rem >> 1; }
        else             { in = dw; out = WdT; Ri = HDIM; Ci = DIM;  ri = rem & 3; ci = rem >> 2; }
        const float* ip = in + (size_t)e * Ri * Ci + (size_t)(ri * 512) * Ci + ci * 64;
        unsigned short* op = out + (size_t)e * Ri * Ci + (size_t)(ci * 64) * Ri + ri * 512;
        const int s = threadIdx.x & 15;      // float4 slot within 64-col row
        const int rb = threadIdx.x >> 4;     // row base 0..15
        // phase 1: batched coalesced fp32 reads -> cvt -> LDS rows [r][c]
#pragma unroll
        for (int ii = 0; ii < 4; ++ii) {
            float4 v[8];
#pragma unroll
            for (int j = 0; j < 8; ++j)
                v[j] = *(const float4*)&ip[(size_t)(rb + 16 * (ii * 8 + j)) * Ci + s * 4];
#pragma unroll
            for (int j = 0; j < 8; ++j) {
                ushort4 h;
                h.x = f2bf(v[j].x); h.y = f2bf(v[j].y); h.z = f2bf(v[j].z); h.w = f2bf(v[j].w);
                *(ushort4*)&lt[rb + 16 * (ii * 8 + j)][s * 4] = h;
            }
        }
        __syncthreads();
        // phase 2: column-gather (8x ds_read_u16, <=2-way bank) -> 1KB/wave stores
        const int w = threadIdx.x >> 6, l = threadIdx.x & 63;
#pragma unroll
        for (int i = 0; i < 16; ++i) {
            int c = w + 4 * i;               // wave-uniform out-row
            u16x8 h;
#pragma unroll
            for (int k = 0; k < 8; ++k) h[k] = lt[l * 8 + k][c];
            *(u16x8*)&op[(size_t)c * Ri + l * 8] = h;
        }
    } else {
        const int wid = (b - NTT) * 4 + (threadIdx.x >> 6);
        const int lane = threadIdx.x & 63;
        if (wid >= T_TOK) return;
        float acc[NE];
#pragma unroll
        for (int e = 0; e < NE; ++e) acc[e] = 0.f;
        const float* xr = x + (size_t)wid * DIM;
        for (int i = lane; i < DIM; i += 64) {
            float xv = xr[i];
            const float* wr = rw + (size_t)i * NE;
#pragma unroll
            for (int e = 0; e < NE; ++e) acc[e] += xv * wr[e];
        }
#pragma unroll
        for (int off = 32; off; off >>= 1) {
#pragma unroll
            for (int e = 0; e < NE; ++e) acc[e] += __shfl_xor(acc[e], off, 64);
        }
        if (lane == 0) {
            float v0 = -1e30f, v1 = -1e30f; int i0 = 0, i1 = 0;
#pragma unroll
            for (int e = 0; e < NE; ++e) {
                float v = acc[e];
                if (v > v0) { v1 = v0; i1 = i0; v0 = v; i0 = e; }
                else if (v > v1) { v1 = v; i1 = e; }
            }
            float e1 = __expf(v1 - v0);
            float s = 1.f + e1;
            top_idx[wid * 2]     = i0;
            top_idx[wid * 2 + 1] = i1;
            top_w[wid * 2]     = 1.f / s;
            top_w[wid * 2 + 1] = e1 / s;
            atomicAdd(&counts[i0], 1);
            atomicAdd(&counts[i1], 1);
        }
    }
}

// ---------------- scan + compact tile list (holes only at the tail)
__global__ void scan_kernel(const int* __restrict__ counts, int* __restrict__ offsets,
                            int* __restrict__ cursors,
                            int* __restrict__ tl_e, int* __restrict__ tl_m) {
    if (threadIdx.x == 0) {
        int run = 0;
        for (int e = 0; e < NE; ++e) { offsets[e] = run; cursors[e] = run; run += counts[e]; }
        int n = 0;
        for (int e = 0; e < NE; ++e) {
            int mt = (counts[e] + 127) >> 7;
            for (int m = 0; m < mt && n < 64; ++m) { tl_e[n] = e; tl_m[n] = m; ++n; }
        }
        for (; n < 64; ++n) tl_e[n] = -1;
    }
}

// ---------------- gather: pack each token's row (bf16) into its 2 experts' segments
__global__ void gather_kernel(const float* __restrict__ x, const int* __restrict__ top_idx,
                              const float* __restrict__ top_w, int* __restrict__ cursors,
                              int* __restrict__ row_tok, float* __restrict__ row_w,
                              unsigned short* __restrict__ Abuf) {
    int t = blockIdx.x;
    __shared__ int pos[2];
    if (threadIdx.x < 2) {
        int k = threadIdx.x;
        int e = top_idx[t * 2 + k];
        int p = atomicAdd(&cursors[e], 1);
        pos[k] = p;
        row_tok[p] = t;
        row_w[p] = top_w[t * 2 + k];
    }
    __syncthreads();
    const float4* xr = (const float4*)(x + (size_t)t * DIM);
    float4 v = xr[threadIdx.x];
    ushort4 b;
    b.x = f2bf(v.x); b.y = f2bf(v.y); b.z = f2bf(v.z); b.w = f2bf(v.w);
    ushort4* A4 = (ushort4*)Abuf;
    A4[(size_t)pos[0] * (DIM / 4) + threadIdx.x] = b;
    A4[(size_t)pos[1] * (DIM / 4) + threadIdx.x] = b;
}

// ---------------- GEMM1: hidden = silu(A @ Wg^T) * (A @ Wu^T), per expert
// BM=128, BN=64, BK=64 (16 steps); 4 waves = 2(m) x 2(gate|up);
// 64KB LDS double-buffered; silu combine via bf16 LDS exchange.  (R10-proven.)
__global__ __launch_bounds__(256, 2)
void gemm1_kernel(const unsigned short* __restrict__ Abuf,
                  const unsigned short* __restrict__ WgT,
                  const unsigned short* __restrict__ WuT,
                  unsigned short* __restrict__ Hbuf,
                  const int* __restrict__ offsets, const int* __restrict__ counts,
                  const int* __restrict__ tl_e, const int* __restrict__ tl_m) {
    const int slot = blockIdx.y;
    const int e = tl_e[slot];
    if (e < 0) return;
    const int mtile = tl_m[slot];
    const int cnt = counts[e];
    const int n0 = blockIdx.x * 64;
    const int row0 = offsets[e] + mtile * 128;

    __shared__ __align__(16) unsigned char lds_raw[65536];
    unsigned short* AsB = (unsigned short*)lds_raw;            // [2][128*64] = 32KB
    unsigned short* BgB = (unsigned short*)(lds_raw + 32768);  // [2][64*64]  = 16KB
    unsigned short* BuB = (unsigned short*)(lds_raw + 49152);  // [2][64*64]  = 16KB
    unsigned short* ex  = (unsigned short*)lds_raw;            // epilogue [2][64][64] bf16 (aliases AsB)

    const int tid = threadIdx.x;
    const int lane = tid & 63;
    const int wave = tid >> 6;
    const int wm = wave >> 1;        // m-half (0,1)
    const int wu = wave & 1;         // 0 = gate, 1 = up

    f32x4 acc[4][4];
#pragma unroll
    for (int i = 0; i < 4; ++i)
#pragma unroll
        for (int j = 0; j < 4; ++j) acc[i][j] = (f32x4){0.f, 0.f, 0.f, 0.f};

    // staging: rows of 64 shorts = 8 x 16B chunks; swizzle chunk ^= row&7
    const int srow = tid >> 3;          // 0..31
    const int sc0 = tid & 7;            // 16B-chunk within 128B row
    const unsigned short* Aab = Abuf + (size_t)row0 * DIM;
    const unsigned short* Bgb = WgT + (size_t)e * HDIM * DIM + (size_t)n0 * DIM;
    const unsigned short* Bub = WuT + (size_t)e * HDIM * DIM + (size_t)n0 * DIM;

    auto stage = [&](int buf, int kt) {
#pragma unroll
        for (int i = 0; i < 4; ++i) {                          // A: 128 rows
            int row = i * 32 + srow;
            int csrc = sc0 ^ (row & 7);
            gload16(Aab + (size_t)row * DIM + kt + csrc * 8,
                    AsB + buf * 8192 + (i * 256 + tid) * 8);
        }
#pragma unroll
        for (int i = 0; i < 2; ++i) {                          // Bg, Bu: 64 rows each
            int row = i * 32 + srow;
            int csrc = sc0 ^ (row & 7);
            size_t go = (size_t)row * DIM + kt + csrc * 8;
            gload16(Bgb + go, BgB + buf * 4096 + (i * 256 + tid) * 8);
            gload16(Bub + go, BuB + buf * 4096 + (i * 256 + tid) * 8);
        }
    };

    const int rsel = lane & 15;
    const int csrcf = lane >> 4;        // fragment k-chunk (0..3)

    stage(0, 0);
    int cur = 0;
    for (int kt = 0; kt < DIM; kt += 64) {
        __syncthreads();
        if (kt + 64 < DIM) stage(cur ^ 1, kt + 64);
        const unsigned short* Ac = AsB + cur * 8192;
        const unsigned short* Bc = (wu ? BuB : BgB) + cur * 4096;
#pragma unroll
        for (int kk = 0; kk < 2; ++kk) {
            bf16x8 af[4], bb[4];
#pragma unroll
            for (int i = 0; i < 4; ++i) {
                int ra = wm * 64 + i * 16 + rsel;
                af[i] = *(const bf16x8*)&Ac[ra * 64 + ((kk * 4 + csrcf) ^ (ra & 7)) * 8];
                int rb = i * 16 + rsel;
                bb[i] = *(const bf16x8*)&Bc[rb * 64 + ((kk * 4 + csrcf) ^ (rb & 7)) * 8];
            }
#pragma unroll
            for (int i = 0; i < 4; ++i)
#pragma unroll
                for (int j = 0; j < 4; ++j)
                    acc[i][j] = __builtin_amdgcn_mfma_f32_16x16x32_bf16(af[i], bb[j], acc[i][j], 0, 0, 0);
        }
        cur ^= 1;
    }

    // ---- epilogue: up-waves export u (bf16) via LDS; gate-waves apply silu(g)*u
    const int c = lane & 15, rbase = (lane >> 4) * 4;
    const int obase = offsets[e];
    __syncthreads();                    // all staging reads done; safe to alias LDS
    if (wu) {
#pragma unroll
        for (int i = 0; i < 4; ++i)
#pragma unroll
            for (int r = 0; r < 4; ++r) {
                int row64 = i * 16 + rbase + r;
#pragma unroll
                for (int j = 0; j < 4; ++j)
                    ex[wm * 4096 + row64 * 64 + j * 16 + c] = f2bf(acc[i][j][r]);
            }
    }
    __syncthreads();
    if (!wu) {
#pragma unroll
        for (int i = 0; i < 4; ++i) {
#pragma unroll
            for (int r = 0; r < 4; ++r) {
                int row64 = i * 16 + rbase + r;
                int lrow = mtile * 128 + wm * 64 + row64;
                if (lrow < cnt) {
                    size_t orow = (size_t)(obase + lrow);
#pragma unroll
                    for (int j = 0; j < 4; ++j) {
                        float g = acc[i][j][r];
                        float u = bf2f(ex[wm * 4096 + row64 * 64 + j * 16 + c]);
                        float h = g * u / (1.f + __expf(-g));
                        Hbuf[orow * HDIM + n0 + j * 16 + c] = f2bf(h);
                    }
                }
            }
        }
    }
}

// ---------------- GEMM2: y[tok] += w * (hidden @ WdT^T)
// 2-phase double-buffered, BK=64, XOR-swizzled LDS (c ^= row&7), K split x2,
// compact tile-list grid.  (R10-proven.)
__global__ __launch_bounds__(256, 2)
void gemm2_kernel(const unsigned short* __restrict__ Hbuf,
                  const unsigned short* __restrict__ WdT,
                  float* __restrict__ y,
                  const int* __restrict__ offsets, const int* __restrict__ counts,
                  const int* __restrict__ row_tok, const float* __restrict__ row_w,
                  const int* __restrict__ tl_e, const int* __restrict__ tl_m) {
    const int slot = blockIdx.y;
    const int e = tl_e[slot];
    if (e < 0) return;
    const int mtile = tl_m[slot];
    const int kc = blockIdx.z;
    const int cnt = counts[e];
    const int n0 = blockIdx.x * 128;
    const int row0 = offsets[e] + mtile * 128;

    __shared__ unsigned short As[2][128 * 64];   // 32 KB
    __shared__ unsigned short Bs[2][128 * 64];   // 32 KB

    const int tid = threadIdx.x;
    const int lane = tid & 63;
    const int wave = tid >> 6;
    const int wm = wave >> 1, wn = wave & 1;

    f32x4 acc[4][4];
#pragma unroll
    for (int i = 0; i < 4; ++i)
#pragma unroll
        for (int j = 0; j < 4; ++j) acc[i][j] = (f32x4){0.f, 0.f, 0.f, 0.f};

    const int srow0 = tid >> 3;          // row within 32-row quarter (+i*32)
    const int sc0 = tid & 7;             // LDS 16B-chunk within 128B row
    const unsigned short* Aab = Hbuf + (size_t)row0 * HDIM;
    const unsigned short* Bbb = WdT + (size_t)e * DIM * HDIM + (size_t)n0 * HDIM;

    auto stage = [&](int buf, int kt) {
#pragma unroll
        for (int i = 0; i < 4; ++i) {
            int row = i * 32 + srow0;
            int csrc = sc0 ^ (row & 7);
            size_t go = (size_t)row * HDIM + kt + csrc * 8;
            int lo = (i * 256 + tid) * 8;
            gload16(Aab + go, &As[buf][lo]);
            gload16(Bbb + go, &Bs[buf][lo]);
        }
    };

    const int rsel = lane & 15;
    const int csrcf = lane >> 4;

    const int kbeg = kc * (HDIM / 2);
    const int kend = kbeg + (HDIM / 2);

    stage(0, kbeg);
    int cur = 0;
    for (int kt = kbeg; kt < kend; kt += 64) {
        __syncthreads();
        if (kt + 64 < kend) stage(cur ^ 1, kt + 64);
        const unsigned short* Ac = As[cur];
        const unsigned short* Bc = Bs[cur];
#pragma unroll
        for (int kk = 0; kk < 2; ++kk) {
            bf16x8 af[4], bf[4];
#pragma unroll
            for (int i = 0; i < 4; ++i) {
                int ra = wm * 64 + i * 16 + rsel;
                af[i] = *(const bf16x8*)&Ac[ra * 64 + ((kk * 4 + csrcf) ^ (ra & 7)) * 8];
                int rb = wn * 64 + i * 16 + rsel;
                bf[i] = *(const bf16x8*)&Bc[rb * 64 + ((kk * 4 + csrcf) ^ (rb & 7)) * 8];
            }
#pragma unroll
            for (int i = 0; i < 4; ++i)
#pragma unroll
                for (int j = 0; j < 4; ++j)
                    acc[i][j] = __builtin_amdgcn_mfma_f32_16x16x32_bf16(af[i], bf[j], acc[i][j], 0, 0, 0);
        }
        cur ^= 1;
    }

    const int c = lane & 15, rbase = (lane >> 4) * 4;
    const int obase = offsets[e];
#pragma unroll
    for (int i = 0; i < 4; ++i) {
#pragma unroll
        for (int r = 0; r < 4; ++r) {
            int lrow = mtile * 128 + wm * 64 + i * 16 + rbase + r;
            if (lrow < cnt) {
                int grow = obase + lrow;
                int tok = row_tok[grow];
                float w = row_w[grow];
#pragma unroll
                for (int j = 0; j < 4; ++j) {
                    atomicAdd(&y[(size_t)tok * DIM + n0 + wn * 64 + j * 16 + c], w * acc[i][j][r]);
                }
            }
        }
    }
}

extern "C" void kernel_launch(void* const* d_in, const int* in_sizes, int n_in,
                              void* d_out, int out_size, void* d_ws, size_t ws_size,
                              hipStream_t stream) {
    const float* x  = (const float*)d_in[0];
    const float* rw = (const float*)d_in[1];
    const float* gw = (const float*)d_in[2];
    const float* uw = (const float*)d_in[3];
    const float* dw = (const float*)d_in[4];
    float* y = (float*)d_out;

    char* ws = (char*)d_ws;
    int*   counts  = (int*)(ws + 0);
    int*   cursors = (int*)(ws + 32);
    int*   offsets = (int*)(ws + 64);
    int*   top_idx = (int*)(ws + 128);
    float* top_w   = (float*)(ws + 128 + 16384);
    int*   row_tok = (int*)(ws + 128 + 32768);
    float* row_w   = (float*)(ws + 128 + 32768 + 16896);
    int*   tl_e    = (int*)(ws + 128 + 32768 + 2 * 16896);
    int*   tl_m    = (int*)(ws + 128 + 32768 + 2 * 16896 + 256);
    size_t off = 128 + 32768 + 2 * 16896 + 512;
    off = (off + 255) & ~(size_t)255;
    unsigned short* Abuf = (unsigned short*)(ws + off); off += (size_t)ROWS_PAD * DIM * 2;
    unsigned short* Hbuf = (unsigned short*)(ws + off); off += (size_t)ROWS_PAD * HDIM * 2;
    unsigned short* WgT  = (unsigned short*)(ws + off); off += (size_t)NE * DIM * HDIM * 2;
    unsigned short* WuT  = (unsigned short*)(ws + off); off += (size_t)NE * DIM * HDIM * 2;
    unsigned short* WdT  = (unsigned short*)(ws + off); off += (size_t)NE * DIM * HDIM * 2;
    if (ws_size < off) return;  // workspace too small: fail loudly (zero output)

    hipMemsetAsync(counts, 0, 32, stream);
    hipMemsetAsync(d_out, 0, (size_t)out_size * 4, stream);

    prep_kernel<<<NTT + T_TOK / 4, 256, 0, stream>>>(gw, uw, dw, WgT, WuT, WdT,
                                                     x, rw, counts, top_idx, top_w);
    scan_kernel<<<1, 64, 0, stream>>>(counts, offsets, cursors, tl_e, tl_m);
    gather_kernel<<<T_TOK, 256, 0, stream>>>(x, top_idx, top_w, cursors, row_tok, row_w, Abuf);

    gemm1_kernel<<<dim3(HDIM / 64, TSLOTS), 256, 0, stream>>>(Abuf, WgT, WuT, Hbuf,
                                                              offsets, counts, tl_e, tl_m);
    gemm2_kernel<<<dim3(DIM / 128, TSLOTS, 2), 256, 0, stream>>>(Hbuf, WdT, y, offsets, counts,
                                                                 row_tok, row_w, tl_e, tl_m);
}

// Round 15
// 263.597 us; speedup vs baseline: 1.0562x; 1.0562x over previous
//
#include <hip/hip_runtime.h>
#include <hip/hip_bf16.h>
#include <stdint.h>

#define T_TOK 2048
#define DIM   1024
#define HDIM  2048
#define NE    8
#define ROWS_PAD 4224   // 4096 routed rows + 128 pad for tile overrun
#define TSLOTS 40       // max live (expert,mtile) pairs: 32 + 7 = 39

typedef __attribute__((ext_vector_type(8))) short bf16x8;
typedef __attribute__((ext_vector_type(8))) unsigned short u16x8;
typedef __attribute__((ext_vector_type(4))) float f32x4;

__device__ __forceinline__ unsigned short f2bf(float f) {
    union { float f; unsigned int u; } v; v.f = f;
    unsigned int r = v.u + 0x7FFF + ((v.u >> 16) & 1);   // round-nearest-even
    return (unsigned short)(r >> 16);
}

__device__ __forceinline__ float bf2f(unsigned short b) {
    union { unsigned int u; float f; } v; v.u = ((unsigned int)b) << 16;
    return v.f;
}

// ---------------- router: logits = x @ rw, top-2 softmax, counts
__global__ void router_kernel(const float* __restrict__ x, const float* __restrict__ rw,
                              int* __restrict__ counts, int* __restrict__ top_idx,
                              float* __restrict__ top_w) {
    int wid = (blockIdx.x * blockDim.x + threadIdx.x) >> 6;
    int lane = threadIdx.x & 63;
    if (wid >= T_TOK) return;
    float acc[NE];
#pragma unroll
    for (int e = 0; e < NE; ++e) acc[e] = 0.f;
    const float* xr = x + (size_t)wid * DIM;
    for (int i = lane; i < DIM; i += 64) {
        float xv = xr[i];
        const float* wr = rw + (size_t)i * NE;
#pragma unroll
        for (int e = 0; e < NE; ++e) acc[e] += xv * wr[e];
    }
#pragma unroll
    for (int off = 32; off; off >>= 1) {
#pragma unroll
        for (int e = 0; e < NE; ++e) acc[e] += __shfl_xor(acc[e], off, 64);
    }
    if (lane == 0) {
        float v0 = -1e30f, v1 = -1e30f; int i0 = 0, i1 = 0;
#pragma unroll
        for (int e = 0; e < NE; ++e) {
            float v = acc[e];
            if (v > v0) { v1 = v0; i1 = i0; v0 = v; i0 = e; }
            else if (v > v1) { v1 = v; i1 = e; }
        }
        float e1 = __expf(v1 - v0);
        float s = 1.f + e1;
        top_idx[wid * 2]     = i0;
        top_idx[wid * 2 + 1] = i1;
        top_w[wid * 2]     = 1.f / s;
        top_w[wid * 2 + 1] = e1 / s;
        atomicAdd(&counts[i0], 1);
        atomicAdd(&counts[i1], 1);
    }
}

// ---------------- scan + compact tile list (holes only at the tail)
__global__ void scan_kernel(const int* __restrict__ counts, int* __restrict__ offsets,
                            int* __restrict__ cursors,
                            int* __restrict__ tl_e, int* __restrict__ tl_m) {
    if (threadIdx.x == 0) {
        int run = 0;
        for (int e = 0; e < NE; ++e) { offsets[e] = run; cursors[e] = run; run += counts[e]; }
        int n = 0;
        for (int e = 0; e < NE; ++e) {
            int mt = (counts[e] + 127) >> 7;
            for (int m = 0; m < mt && n < 64; ++m) { tl_e[n] = e; tl_m[n] = m; ++n; }
        }
        for (; n < 64; ++n) tl_e[n] = -1;
    }
}

// ---------------- gather: pack each token's row (bf16) into its 2 experts' segments
__global__ void gather_kernel(const float* __restrict__ x, const int* __restrict__ top_idx,
                              const float* __restrict__ top_w, int* __restrict__ cursors,
                              int* __restrict__ row_tok, float* __restrict__ row_w,
                              unsigned short* __restrict__ Abuf) {
    int t = blockIdx.x;
    __shared__ int pos[2];
    if (threadIdx.x < 2) {
        int k = threadIdx.x;
        int e = top_idx[t * 2 + k];
        int p = atomicAdd(&cursors[e], 1);
        pos[k] = p;
        row_tok[p] = t;
        row_w[p] = top_w[t * 2 + k];
    }
    __syncthreads();
    const float4* xr = (const float4*)(x + (size_t)t * DIM);
    float4 v = xr[threadIdx.x];
    ushort4 b;
    b.x = f2bf(v.x); b.y = f2bf(v.y); b.z = f2bf(v.z); b.w = f2bf(v.w);
    ushort4* A4 = (ushort4*)Abuf;
    A4[(size_t)pos[0] * (DIM / 4) + threadIdx.x] = b;
    A4[(size_t)pos[1] * (DIM / 4) + threadIdx.x] = b;
}

// ---------------- GEMM1: hidden = silu(A @ Wg^T) * (A @ Wu^T), per expert
// BM=128, BN=64, BK=64; 4 waves = 2(m) x 2(gate|up); 64KB LDS double-buffered.
// PURE register-staged depth-2 pipeline: every global load has a register dest,
// so the COMPILER inserts the counted vmcnt at each use. Barriers are
// lgkmcnt(0)+s_barrier only (no vmcnt drain) -> in-flight loads survive.
__global__ __launch_bounds__(256, 2)
void gemm1_kernel(const unsigned short* __restrict__ Abuf,
                  const float* __restrict__ gw,
                  const float* __restrict__ uw,
                  unsigned short* __restrict__ Hbuf,
                  const int* __restrict__ offsets, const int* __restrict__ counts,
                  const int* __restrict__ tl_e, const int* __restrict__ tl_m) {
    const int slot = blockIdx.y;
    const int e = tl_e[slot];
    if (e < 0) return;
    const int mtile = tl_m[slot];
    const int cnt = counts[e];
    const int n0 = blockIdx.x * 64;
    const int row0 = offsets[e] + mtile * 128;

    __shared__ __align__(16) unsigned char lds_raw[65536];
    unsigned short* AsB = (unsigned short*)lds_raw;            // [2][128*64] = 32KB
    unsigned short* BgB = (unsigned short*)(lds_raw + 32768);  // [2][64*64]  = 16KB
    unsigned short* BuB = (unsigned short*)(lds_raw + 49152);  // [2][64*64]  = 16KB
    unsigned short* ex  = (unsigned short*)lds_raw;            // epilogue [2][64][64] bf16 (aliases AsB)

    const int tid = threadIdx.x;
    const int lane = tid & 63;
    const int wave = tid >> 6;
    const int wm = wave >> 1;        // m-half (0,1)
    const int wu = wave & 1;         // 0 = gate, 1 = up

    f32x4 acc[4][4];
#pragma unroll
    for (int i = 0; i < 4; ++i)
#pragma unroll
        for (int j = 0; j < 4; ++j) acc[i][j] = (f32x4){0.f, 0.f, 0.f, 0.f};

    // A: 4 u16x8 loads/step (rows i*32+srow, chunk sc0, inverse-swizzled source)
    const int srow = tid >> 3;          // 0..31
    const int sc0 = tid & 7;
    const unsigned short* Aab = Abuf + (size_t)row0 * DIM;

    // B: thread owns n = tid&63, chunks c = (tid>>6), (tid>>6)+4 (32 loads/step)
    const int bn = tid & 63;
    const int bc0 = tid >> 6;           // 0..3
    const float* Bgb = gw + (size_t)e * DIM * HDIM + n0 + bn;
    const float* Bub = uw + (size_t)e * DIM * HDIM + n0 + bn;

    u16x8 aT0[4], aT1[4];
    float bg0[2][8], bu0[2][8], bg1[2][8], bu1[2][8];

#define G1_ALOAD(aT, kt) do {                                              \
    _Pragma("unroll") for (int i = 0; i < 4; ++i) {                        \
        int row_ = i * 32 + srow;                                          \
        int csrc_ = sc0 ^ (row_ & 7);                                      \
        aT[i] = *(const u16x8*)&Aab[(size_t)row_ * DIM + (kt) + csrc_ * 8];\
    } } while (0)

#define G1_AWRITE(aT, buf) do {                                            \
    _Pragma("unroll") for (int i = 0; i < 4; ++i)                          \
        *(u16x8*)&AsB[(buf) * 8192 + (i * 256 + tid) * 8] = aT[i];         \
    } while (0)

#define G1_BLOAD(bg, bu, kt) do {                                          \
    _Pragma("unroll") for (int cc = 0; cc < 2; ++cc) {                     \
        int c_ = bc0 + cc * 4;                                             \
        const float* gs_ = Bgb + (size_t)((kt) + c_ * 8) * HDIM;           \
        const float* us_ = Bub + (size_t)((kt) + c_ * 8) * HDIM;           \
        _Pragma("unroll") for (int jj = 0; jj < 8; ++jj) {                 \
            bg[cc][jj] = gs_[(size_t)jj * HDIM];                           \
            bu[cc][jj] = us_[(size_t)jj * HDIM];                           \
        } } } while (0)

#define G1_BWRITE(bg, bu, buf) do {                                        \
    _Pragma("unroll") for (int cc = 0; cc < 2; ++cc) {                     \
        int c_ = bc0 + cc * 4;                                             \
        int la_ = bn * 64 + ((c_ ^ (bn & 7)) * 8);                         \
        u16x8 vg_, vu_;                                                    \
        _Pragma("unroll") for (int jj = 0; jj < 8; ++jj) {                 \
            vg_[jj] = f2bf(bg[cc][jj]);                                    \
            vu_[jj] = f2bf(bu[cc][jj]);                                    \
        }                                                                  \
        *(u16x8*)&BgB[(buf) * 4096 + la_] = vg_;                           \
        *(u16x8*)&BuB[(buf) * 4096 + la_] = vu_;                           \
    } } while (0)

    const int rsel = lane & 15;
    const int csrcf = lane >> 4;        // fragment k-chunk (0..3)

#define G1_COMPUTE(buf) do {                                               \
    const unsigned short* Ac_ = AsB + (buf) * 8192;                        \
    const unsigned short* Bc_ = (wu ? BuB : BgB) + (buf) * 4096;           \
    _Pragma("unroll") for (int kk = 0; kk < 2; ++kk) {                     \
        bf16x8 af_[4], bb_[4];                                             \
        _Pragma("unroll") for (int i = 0; i < 4; ++i) {                    \
            int ra_ = wm * 64 + i * 16 + rsel;                             \
            af_[i] = *(const bf16x8*)&Ac_[ra_ * 64 + ((kk * 4 + csrcf) ^ (ra_ & 7)) * 8]; \
            int rb_ = i * 16 + rsel;                                       \
            bb_[i] = *(const bf16x8*)&Bc_[rb_ * 64 + ((kk * 4 + csrcf) ^ (rb_ & 7)) * 8]; \
        }                                                                  \
        _Pragma("unroll") for (int i = 0; i < 4; ++i)                      \
            _Pragma("unroll") for (int j = 0; j < 4; ++j)                  \
                acc[i][j] = __builtin_amdgcn_mfma_f32_16x16x32_bf16(af_[i], bb_[j], acc[i][j], 0, 0, 0); \
    } } while (0)

#define G1_BAR() do {                                                      \
    asm volatile("s_waitcnt lgkmcnt(0)" ::: "memory");                     \
    __builtin_amdgcn_s_barrier();                                          \
    } while (0)

    // prologue: tile0+tile1 loads in flight; tile0 into buf0
    G1_ALOAD(aT0, 0);   G1_BLOAD(bg0, bu0, 0);
    G1_ALOAD(aT1, 64);  G1_BLOAD(bg1, bu1, 64);
    G1_AWRITE(aT0, 0);  G1_BWRITE(bg0, bu0, 0);   // compiler waits set0 loads only
    G1_BAR();

    for (int k = 0; k < 16; k += 2) {
        // even: compute tile k (buf0); write tile k+1 (buf1); load tile k+2 -> set0
        if (k + 2 < 16) { G1_ALOAD(aT0, (k + 2) * 64); G1_BLOAD(bg0, bu0, (k + 2) * 64); }
        G1_COMPUTE(0);
        G1_AWRITE(aT1, 1); G1_BWRITE(bg1, bu1, 1);
        G1_BAR();
        // odd: compute tile k+1 (buf1); write tile k+2 (buf0); load tile k+3 -> set1
        if (k + 3 < 16) { G1_ALOAD(aT1, (k + 3) * 64); G1_BLOAD(bg1, bu1, (k + 3) * 64); }
        G1_COMPUTE(1);
        if (k + 2 < 16) { G1_AWRITE(aT0, 0); G1_BWRITE(bg0, bu0, 0); }
        G1_BAR();
    }

    // ---- epilogue: up-waves export u (bf16) via LDS; gate-waves apply silu(g)*u
    const int c = lane & 15, rbase = (lane >> 4) * 4;
    const int obase = offsets[e];
    __syncthreads();                    // full drain; safe to alias LDS
    if (wu) {
#pragma unroll
        for (int i = 0; i < 4; ++i)
#pragma unroll
            for (int r = 0; r < 4; ++r) {
                int row64 = i * 16 + rbase + r;
#pragma unroll
                for (int j = 0; j < 4; ++j)
                    ex[wm * 4096 + row64 * 64 + j * 16 + c] = f2bf(acc[i][j][r]);
            }
    }
    __syncthreads();
    if (!wu) {
#pragma unroll
        for (int i = 0; i < 4; ++i) {
#pragma unroll
            for (int r = 0; r < 4; ++r) {
                int row64 = i * 16 + rbase + r;
                int lrow = mtile * 128 + wm * 64 + row64;
                if (lrow < cnt) {
                    size_t orow = (size_t)(obase + lrow);
#pragma unroll
                    for (int j = 0; j < 4; ++j) {
                        float g = acc[i][j][r];
                        float u = bf2f(ex[wm * 4096 + row64 * 64 + j * 16 + c]);
                        float h = g * u / (1.f + __expf(-g));
                        Hbuf[orow * HDIM + n0 + j * 16 + c] = f2bf(h);
                    }
                }
            }
        }
    }
}

// ---------------- GEMM2: y[tok] += w * (hidden @ Wd^T)
// BM=128, BN=128, BK=64, K split x2. Same register-staged depth-2 pipeline.
__global__ __launch_bounds__(256, 2)
void gemm2_kernel(const unsigned short* __restrict__ Hbuf,
                  const float* __restrict__ dw,
                  float* __restrict__ y,
                  const int* __restrict__ offsets, const int* __restrict__ counts,
                  const int* __restrict__ row_tok, const float* __restrict__ row_w,
                  const int* __restrict__ tl_e, const int* __restrict__ tl_m) {
    const int slot = blockIdx.y;
    const int e = tl_e[slot];
    if (e < 0) return;
    const int mtile = tl_m[slot];
    const int kc = blockIdx.z;
    const int cnt = counts[e];
    const int n0 = blockIdx.x * 128;
    const int row0 = offsets[e] + mtile * 128;

    __shared__ unsigned short As[2][128 * 64];   // 32 KB
    __shared__ unsigned short Bs[2][128 * 64];   // 32 KB

    const int tid = threadIdx.x;
    const int lane = tid & 63;
    const int wave = tid >> 6;
    const int wm = wave >> 1, wn = wave & 1;

    f32x4 acc[4][4];
#pragma unroll
    for (int i = 0; i < 4; ++i)
#pragma unroll
        for (int j = 0; j < 4; ++j) acc[i][j] = (f32x4){0.f, 0.f, 0.f, 0.f};

    const int srow = tid >> 3;
    const int sc0 = tid & 7;
    const unsigned short* Aab = Hbuf + (size_t)row0 * HDIM;

    const int bn = tid & 127;
    const int bc0 = (tid >> 7) * 4;     // 0 or 4
    const float* Bbb = dw + (size_t)e * HDIM * DIM + n0 + bn;

    u16x8 aT0[4], aT1[4];
    float bl0[4][8], bl1[4][8];

#define G2_ALOAD(aT, kt) do {                                              \
    _Pragma("unroll") for (int i = 0; i < 4; ++i) {                        \
        int row_ = i * 32 + srow;                                          \
        int csrc_ = sc0 ^ (row_ & 7);                                      \
        aT[i] = *(const u16x8*)&Aab[(size_t)row_ * HDIM + (kt) + csrc_ * 8]; \
    } } while (0)

#define G2_AWRITE(aT, buf) do {                                            \
    _Pragma("unroll") for (int i = 0; i < 4; ++i)                          \
        *(u16x8*)&As[buf][(i * 256 + tid) * 8] = aT[i];                    \
    } while (0)

#define G2_BLOAD(bl, kt) do {                                              \
    _Pragma("unroll") for (int cc = 0; cc < 4; ++cc) {                     \
        const float* bs_ = Bbb + (size_t)((kt) + (bc0 + cc) * 8) * DIM;    \
        _Pragma("unroll") for (int jj = 0; jj < 8; ++jj)                   \
            bl[cc][jj] = bs_[(size_t)jj * DIM];                            \
    } } while (0)

#define G2_BWRITE(bl, buf) do {                                            \
    _Pragma("unroll") for (int cc = 0; cc < 4; ++cc) {                     \
        int c_ = bc0 + cc;                                                 \
        int la_ = bn * 64 + ((c_ ^ (bn & 7)) * 8);                         \
        u16x8 v_;                                                          \
        _Pragma("unroll") for (int jj = 0; jj < 8; ++jj) v_[jj] = f2bf(bl[cc][jj]); \
        *(u16x8*)&Bs[buf][la_] = v_;                                       \
    } } while (0)

    const int rsel = lane & 15;
    const int csrcf = lane >> 4;

#define G2_COMPUTE(buf) do {                                               \
    const unsigned short* Ac_ = As[buf];                                   \
    const unsigned short* Bc_ = Bs[buf];                                   \
    _Pragma("unroll") for (int kk = 0; kk < 2; ++kk) {                     \
        bf16x8 af_[4], bf_[4];                                             \
        _Pragma("unroll") for (int i = 0; i < 4; ++i) {                    \
            int ra_ = wm * 64 + i * 16 + rsel;                             \
            af_[i] = *(const bf16x8*)&Ac_[ra_ * 64 + ((kk * 4 + csrcf) ^ (ra_ & 7)) * 8]; \
            int rb_ = wn * 64 + i * 16 + rsel;                             \
            bf_[i] = *(const bf16x8*)&Bc_[rb_ * 64 + ((kk * 4 + csrcf) ^ (rb_ & 7)) * 8]; \
        }                                                                  \
        _Pragma("unroll") for (int i = 0; i < 4; ++i)                      \
            _Pragma("unroll") for (int j = 0; j < 4; ++j)                  \
                acc[i][j] = __builtin_amdgcn_mfma_f32_16x16x32_bf16(af_[i], bf_[j], acc[i][j], 0, 0, 0); \
    } } while (0)

#define G2_BAR() do {                                                      \
    asm volatile("s_waitcnt lgkmcnt(0)" ::: "memory");                     \
    __builtin_amdgcn_s_barrier();                                          \
    } while (0)

    const int kbeg = kc * (HDIM / 2);

    G2_ALOAD(aT0, kbeg);      G2_BLOAD(bl0, kbeg);
    G2_ALOAD(aT1, kbeg + 64); G2_BLOAD(bl1, kbeg + 64);
    G2_AWRITE(aT0, 0);        G2_BWRITE(bl0, 0);
    G2_BAR();

    for (int k = 0; k < 16; k += 2) {
        if (k + 2 < 16) { G2_ALOAD(aT0, kbeg + (k + 2) * 64); G2_BLOAD(bl0, kbeg + (k + 2) * 64); }
        G2_COMPUTE(0);
        G2_AWRITE(aT1, 1); G2_BWRITE(bl1, 1);
        G2_BAR();
        if (k + 3 < 16) { G2_ALOAD(aT1, kbeg + (k + 3) * 64); G2_BLOAD(bl1, kbeg + (k + 3) * 64); }
        G2_COMPUTE(1);
        if (k + 2 < 16) { G2_AWRITE(aT0, 0); G2_BWRITE(bl0, 0); }
        G2_BAR();
    }

    const int c = lane & 15, rbase = (lane >> 4) * 4;
    const int obase = offsets[e];
#pragma unroll
    for (int i = 0; i < 4; ++i) {
#pragma unroll
        for (int r = 0; r < 4; ++r) {
            int lrow = mtile * 128 + wm * 64 + i * 16 + rbase + r;
            if (lrow < cnt) {
                int grow = obase + lrow;
                int tok = row_tok[grow];
                float w = row_w[grow];
#pragma unroll
                for (int j = 0; j < 4; ++j) {
                    atomicAdd(&y[(size_t)tok * DIM + n0 + wn * 64 + j * 16 + c], w * acc[i][j][r]);
                }
            }
        }
    }
}

extern "C" void kernel_launch(void* const* d_in, const int* in_sizes, int n_in,
                              void* d_out, int out_size, void* d_ws, size_t ws_size,
                              hipStream_t stream) {
    const float* x  = (const float*)d_in[0];
    const float* rw = (const float*)d_in[1];
    const float* gw = (const float*)d_in[2];
    const float* uw = (const float*)d_in[3];
    const float* dw = (const float*)d_in[4];
    float* y = (float*)d_out;

    char* ws = (char*)d_ws;
    int*   counts  = (int*)(ws + 0);
    int*   cursors = (int*)(ws + 32);
    int*   offsets = (int*)(ws + 64);
    int*   top_idx = (int*)(ws + 128);
    float* top_w   = (float*)(ws + 128 + 16384);
    int*   row_tok = (int*)(ws + 128 + 32768);
    float* row_w   = (float*)(ws + 128 + 32768 + 16896);
    int*   tl_e    = (int*)(ws + 128 + 32768 + 2 * 16896);
    int*   tl_m    = (int*)(ws + 128 + 32768 + 2 * 16896 + 256);
    size_t off = 128 + 32768 + 2 * 16896 + 512;
    off = (off + 255) & ~(size_t)255;
    unsigned short* Abuf = (unsigned short*)(ws + off); off += (size_t)ROWS_PAD * DIM * 2;
    unsigned short* Hbuf = (unsigned short*)(ws + off); off += (size_t)ROWS_PAD * HDIM * 2;
    if (ws_size < off) return;  // workspace too small: fail loudly (zero output)

    hipMemsetAsync(counts, 0, 32, stream);
    hipMemsetAsync(d_out, 0, (size_t)out_size * 4, stream);

    router_kernel<<<T_TOK / 4, 256, 0, stream>>>(x, rw, counts, top_idx, top_w);
    scan_kernel<<<1, 64, 0, stream>>>(counts, offsets, cursors, tl_e, tl_m);
    gather_kernel<<<T_TOK, 256, 0, stream>>>(x, top_idx, top_w, cursors, row_tok, row_w, Abuf);

    gemm1_kernel<<<dim3(HDIM / 64, TSLOTS), 256, 0, stream>>>(Abuf, gw, uw, Hbuf,
                                                              offsets, counts, tl_e, tl_m);
    gemm2_kernel<<<dim3(DIM / 128, TSLOTS, 2), 256, 0, stream>>>(Hbuf, dw, y, offsets, counts,
                                                                 row_tok, row_w, tl_e, tl_m);
}

// Round 16
// 246.282 us; speedup vs baseline: 1.1304x; 1.0703x over previous
//
#include <hip/hip_runtime.h>
#include <hip/hip_bf16.h>
#include <stdint.h>

#define T_TOK 2048
#define DIM   1024
#define HDIM  2048
#define NE    8
#define ROWS_PAD 4224   // 4096 routed rows + 128 pad for tile overrun
#define TSLOTS 40       // max live (expert,mtile) pairs: 32 + 7 = 39

typedef __attribute__((ext_vector_type(8))) short bf16x8;
typedef __attribute__((ext_vector_type(8))) unsigned short u16x8;
typedef __attribute__((ext_vector_type(4))) float f32x4;
typedef __attribute__((ext_vector_type(4))) unsigned int u32x4;

// hardware RNE converts (compiler emits v_cvt_pk_bf16_f32 / single cvt)
__device__ __forceinline__ unsigned short f2bf(float f) {
    union { __hip_bfloat16 h; unsigned short u; } cv;
    cv.h = __float2bfloat16(f);
    return cv.u;
}
__device__ __forceinline__ unsigned int f2bf2(float lo, float hi) {
    union { __hip_bfloat162 h; unsigned int u; } cv;
    cv.h = __float22bfloat162_rn(make_float2(lo, hi));
    return cv.u;
}
__device__ __forceinline__ float bf2f(unsigned short b) {
    union { unsigned int u; float f; } v; v.u = ((unsigned int)b) << 16;
    return v.f;
}

__device__ __forceinline__ void gload16(const void* g, void* l) {
    __builtin_amdgcn_global_load_lds(
        (const __attribute__((address_space(1))) void*)g,
        (__attribute__((address_space(3))) void*)l, 16, 0, 0);
}

// ---------------- router: logits = x @ rw, top-2 softmax, counts
__global__ void router_kernel(const float* __restrict__ x, const float* __restrict__ rw,
                              int* __restrict__ counts, int* __restrict__ top_idx,
                              float* __restrict__ top_w) {
    int wid = (blockIdx.x * blockDim.x + threadIdx.x) >> 6;
    int lane = threadIdx.x & 63;
    if (wid >= T_TOK) return;
    float acc[NE];
#pragma unroll
    for (int e = 0; e < NE; ++e) acc[e] = 0.f;
    const float* xr = x + (size_t)wid * DIM;
    for (int i = lane; i < DIM; i += 64) {
        float xv = xr[i];
        const float* wr = rw + (size_t)i * NE;
#pragma unroll
        for (int e = 0; e < NE; ++e) acc[e] += xv * wr[e];
    }
#pragma unroll
    for (int off = 32; off; off >>= 1) {
#pragma unroll
        for (int e = 0; e < NE; ++e) acc[e] += __shfl_xor(acc[e], off, 64);
    }
    if (lane == 0) {
        float v0 = -1e30f, v1 = -1e30f; int i0 = 0, i1 = 0;
#pragma unroll
        for (int e = 0; e < NE; ++e) {
            float v = acc[e];
            if (v > v0) { v1 = v0; i1 = i0; v0 = v; i0 = e; }
            else if (v > v1) { v1 = v; i1 = e; }
        }
        float e1 = __expf(v1 - v0);
        float s = 1.f + e1;
        top_idx[wid * 2]     = i0;
        top_idx[wid * 2 + 1] = i1;
        top_w[wid * 2]     = 1.f / s;
        top_w[wid * 2 + 1] = e1 / s;
        atomicAdd(&counts[i0], 1);
        atomicAdd(&counts[i1], 1);
    }
}

// ---------------- scan + compact tile list (holes only at the tail)
__global__ void scan_kernel(const int* __restrict__ counts, int* __restrict__ offsets,
                            int* __restrict__ cursors,
                            int* __restrict__ tl_e, int* __restrict__ tl_m) {
    if (threadIdx.x == 0) {
        int run = 0;
        for (int e = 0; e < NE; ++e) { offsets[e] = run; cursors[e] = run; run += counts[e]; }
        int n = 0;
        for (int e = 0; e < NE; ++e) {
            int mt = (counts[e] + 127) >> 7;
            for (int m = 0; m < mt && n < 64; ++m) { tl_e[n] = e; tl_m[n] = m; ++n; }
        }
        for (; n < 64; ++n) tl_e[n] = -1;
    }
}

// ---------------- gather: pack each token's row (bf16) into its 2 experts' segments
__global__ void gather_kernel(const float* __restrict__ x, const int* __restrict__ top_idx,
                              const float* __restrict__ top_w, int* __restrict__ cursors,
                              int* __restrict__ row_tok, float* __restrict__ row_w,
                              unsigned short* __restrict__ Abuf) {
    int t = blockIdx.x;
    __shared__ int pos[2];
    if (threadIdx.x < 2) {
        int k = threadIdx.x;
        int e = top_idx[t * 2 + k];
        int p = atomicAdd(&cursors[e], 1);
        pos[k] = p;
        row_tok[p] = t;
        row_w[p] = top_w[t * 2 + k];
    }
    __syncthreads();
    const float4* xr = (const float4*)(x + (size_t)t * DIM);
    float4 v = xr[threadIdx.x];
    unsigned int lo = f2bf2(v.x, v.y), hi = f2bf2(v.z, v.w);
    uint2 b; b.x = lo; b.y = hi;
    uint2* A4 = (uint2*)Abuf;
    A4[(size_t)pos[0] * (DIM / 4) + threadIdx.x] = b;
    A4[(size_t)pos[1] * (DIM / 4) + threadIdx.x] = b;
}

// ---------------- GEMM1: hidden = silu(A @ Wg^T) * (A @ Wu^T), per expert
// BM=128, BN=64, BK=64; 4 waves = 2(m) x 2(gate|up); 64KB LDS double-buffered.
// B staged directly from fp32 gw/uw (depth-1 reg prefetch, write-late),
// converted with v_cvt_pk_bf16_f32. A via global_load_lds.  (R12 schedule.)
__global__ __launch_bounds__(256, 2)
void gemm1_kernel(const unsigned short* __restrict__ Abuf,
                  const float* __restrict__ gw,
                  const float* __restrict__ uw,
                  unsigned short* __restrict__ Hbuf,
                  const int* __restrict__ offsets, const int* __restrict__ counts,
                  const int* __restrict__ tl_e, const int* __restrict__ tl_m) {
    const int slot = blockIdx.y;
    const int e = tl_e[slot];
    if (e < 0) return;
    const int mtile = tl_m[slot];
    const int cnt = counts[e];
    const int n0 = blockIdx.x * 64;
    const int row0 = offsets[e] + mtile * 128;

    __shared__ __align__(16) unsigned char lds_raw[65536];
    unsigned short* AsB = (unsigned short*)lds_raw;            // [2][128*64] = 32KB
    unsigned short* BgB = (unsigned short*)(lds_raw + 32768);  // [2][64*64]  = 16KB
    unsigned short* BuB = (unsigned short*)(lds_raw + 49152);  // [2][64*64]  = 16KB
    unsigned short* ex  = (unsigned short*)lds_raw;            // epilogue [2][64][64] bf16 (aliases AsB)

    const int tid = threadIdx.x;
    const int lane = tid & 63;
    const int wave = tid >> 6;
    const int wm = wave >> 1;        // m-half (0,1)
    const int wu = wave & 1;         // 0 = gate, 1 = up

    f32x4 acc[4][4];
#pragma unroll
    for (int i = 0; i < 4; ++i)
#pragma unroll
        for (int j = 0; j < 4; ++j) acc[i][j] = (f32x4){0.f, 0.f, 0.f, 0.f};

    // A staging via dma (4 loads/thread/step)
    const int srow = tid >> 3;          // 0..31
    const int sc0 = tid & 7;
    const unsigned short* Aab = Abuf + (size_t)row0 * DIM;

    auto stageA = [&](int buf, int kt) {
#pragma unroll
        for (int i = 0; i < 4; ++i) {                          // 128 rows
            int row = i * 32 + srow;
            int csrc = sc0 ^ (row & 7);
            gload16(Aab + (size_t)row * DIM + kt + csrc * 8,
                    AsB + buf * 8192 + (i * 256 + tid) * 8);
        }
    };

    // B: thread owns n = tid&63, chunks c = (tid>>6), (tid>>6)+4 (32 loads/step)
    const int bn = tid & 63;
    const int bc0 = tid >> 6;           // 0..3
    const float* Bgb = gw + (size_t)e * DIM * HDIM + n0 + bn;
    const float* Bub = uw + (size_t)e * DIM * HDIM + n0 + bn;

    float bgl[2][8], bul[2][8];
    auto bload = [&](int kt) {
#pragma unroll
        for (int cc = 0; cc < 2; ++cc) {
            int c = bc0 + cc * 4;
            const float* gs = Bgb + (size_t)(kt + c * 8) * HDIM;
            const float* us = Bub + (size_t)(kt + c * 8) * HDIM;
#pragma unroll
            for (int jj = 0; jj < 8; ++jj) {
                bgl[cc][jj] = gs[(size_t)jj * HDIM];
                bul[cc][jj] = us[(size_t)jj * HDIM];
            }
        }
    };
    auto bwrite = [&](int buf) {
#pragma unroll
        for (int cc = 0; cc < 2; ++cc) {
            int c = bc0 + cc * 4;
            int la = bn * 64 + ((c ^ (bn & 7)) * 8);
            u32x4 vg, vu;
#pragma unroll
            for (int p = 0; p < 4; ++p) {
                vg[p] = f2bf2(bgl[cc][2 * p], bgl[cc][2 * p + 1]);
                vu[p] = f2bf2(bul[cc][2 * p], bul[cc][2 * p + 1]);
            }
            *(u32x4*)&BgB[buf * 4096 + la] = vg;
            *(u32x4*)&BuB[buf * 4096 + la] = vu;
        }
    };

    const int rsel = lane & 15;
    const int csrcf = lane >> 4;        // fragment k-chunk (0..3)

    stageA(0, 0);
    bload(0);
    bwrite(0);
    int cur = 0;
    for (int kt = 0; kt < DIM; kt += 64) {
        __syncthreads();                // buf[cur] ready
        const bool pre = (kt + 64 < DIM);
        if (pre) { stageA(cur ^ 1, kt + 64); bload(kt + 64); }   // issue early
        const unsigned short* Ac = AsB + cur * 8192;
        const unsigned short* Bc = (wu ? BuB : BgB) + cur * 4096;
#pragma unroll
        for (int kk = 0; kk < 2; ++kk) {
            bf16x8 af[4], bb[4];
#pragma unroll
            for (int i = 0; i < 4; ++i) {
                int ra = wm * 64 + i * 16 + rsel;
                af[i] = *(const bf16x8*)&Ac[ra * 64 + ((kk * 4 + csrcf) ^ (ra & 7)) * 8];
                int rb = i * 16 + rsel;
                bb[i] = *(const bf16x8*)&Bc[rb * 64 + ((kk * 4 + csrcf) ^ (rb & 7)) * 8];
            }
#pragma unroll
            for (int i = 0; i < 4; ++i)
#pragma unroll
                for (int j = 0; j < 4; ++j)
                    acc[i][j] = __builtin_amdgcn_mfma_f32_16x16x32_bf16(af[i], bb[j], acc[i][j], 0, 0, 0);
        }
        if (pre) bwrite(cur ^ 1);       // write late (loads covered by MFMAs)
        cur ^= 1;
    }

    // ---- epilogue: up-waves export u (bf16) via LDS; gate-waves apply silu(g)*u
    const int c = lane & 15, rbase = (lane >> 4) * 4;
    const int obase = offsets[e];
    __syncthreads();                    // all staging reads done; safe to alias LDS
    if (wu) {
#pragma unroll
        for (int i = 0; i < 4; ++i)
#pragma unroll
            for (int r = 0; r < 4; ++r) {
                int row64 = i * 16 + rbase + r;
#pragma unroll
                for (int j = 0; j < 4; ++j)
                    ex[wm * 4096 + row64 * 64 + j * 16 + c] = f2bf(acc[i][j][r]);
            }
    }
    __syncthreads();
    if (!wu) {
#pragma unroll
        for (int i = 0; i < 4; ++i) {
#pragma unroll
            for (int r = 0; r < 4; ++r) {
                int row64 = i * 16 + rbase + r;
                int lrow = mtile * 128 + wm * 64 + row64;
                if (lrow < cnt) {
                    size_t orow = (size_t)(obase + lrow);
#pragma unroll
                    for (int j = 0; j < 4; ++j) {
                        float g = acc[i][j][r];
                        float u = bf2f(ex[wm * 4096 + row64 * 64 + j * 16 + c]);
                        float h = g * u / (1.f + __expf(-g));
                        Hbuf[orow * HDIM + n0 + j * 16 + c] = f2bf(h);
                    }
                }
            }
        }
    }
}

// ---------------- GEMM2: y[tok] += w * (hidden @ Wd^T)
// BM=128, BN=128, BK=64, K split x2. B staged directly from fp32 dw with
// v_cvt_pk converts. A (Hbuf) via global_load_lds.  (R12 schedule.)
__global__ __launch_bounds__(256, 2)
void gemm2_kernel(const unsigned short* __restrict__ Hbuf,
                  const float* __restrict__ dw,
                  float* __restrict__ y,
                  const int* __restrict__ offsets, const int* __restrict__ counts,
                  const int* __restrict__ row_tok, const float* __restrict__ row_w,
                  const int* __restrict__ tl_e, const int* __restrict__ tl_m) {
    const int slot = blockIdx.y;
    const int e = tl_e[slot];
    if (e < 0) return;
    const int mtile = tl_m[slot];
    const int kc = blockIdx.z;
    const int cnt = counts[e];
    const int n0 = blockIdx.x * 128;
    const int row0 = offsets[e] + mtile * 128;

    __shared__ unsigned short As[2][128 * 64];   // 32 KB
    __shared__ unsigned short Bs[2][128 * 64];   // 32 KB

    const int tid = threadIdx.x;
    const int lane = tid & 63;
    const int wave = tid >> 6;
    const int wm = wave >> 1, wn = wave & 1;

    f32x4 acc[4][4];
#pragma unroll
    for (int i = 0; i < 4; ++i)
#pragma unroll
        for (int j = 0; j < 4; ++j) acc[i][j] = (f32x4){0.f, 0.f, 0.f, 0.f};

    const int srow0 = tid >> 3;
    const int sc0 = tid & 7;
    const unsigned short* Aab = Hbuf + (size_t)row0 * HDIM;

    auto stageA = [&](int buf, int kt) {
#pragma unroll
        for (int i = 0; i < 4; ++i) {
            int row = i * 32 + srow0;
            int csrc = sc0 ^ (row & 7);
            gload16(Aab + (size_t)row * HDIM + kt + csrc * 8,
                    &As[buf][(i * 256 + tid) * 8]);
        }
    };

    // B: thread owns n = tid&127, chunks c = (tid>>7)*4 + 0..3 (32 loads/step)
    const int bn = tid & 127;
    const int bc0 = (tid >> 7) * 4;     // 0 or 4
    const float* Bbb = dw + (size_t)e * HDIM * DIM + n0 + bn;

    float bl[4][8];
    auto bload = [&](int kt) {
#pragma unroll
        for (int cc = 0; cc < 4; ++cc) {
            const float* bs = Bbb + (size_t)(kt + (bc0 + cc) * 8) * DIM;
#pragma unroll
            for (int jj = 0; jj < 8; ++jj)
                bl[cc][jj] = bs[(size_t)jj * DIM];
        }
    };
    auto bwrite = [&](int buf) {
#pragma unroll
        for (int cc = 0; cc < 4; ++cc) {
            int c = bc0 + cc;
            int la = bn * 64 + ((c ^ (bn & 7)) * 8);
            u32x4 v;
#pragma unroll
            for (int p = 0; p < 4; ++p)
                v[p] = f2bf2(bl[cc][2 * p], bl[cc][2 * p + 1]);
            *(u32x4*)&Bs[buf][la] = v;
        }
    };

    const int rsel = lane & 15;
    const int csrcf = lane >> 4;

    const int kbeg = kc * (HDIM / 2);
    const int kend = kbeg + (HDIM / 2);

    stageA(0, kbeg);
    bload(kbeg);
    bwrite(0);
    int cur = 0;
    for (int kt = kbeg; kt < kend; kt += 64) {
        __syncthreads();
        const bool pre = (kt + 64 < kend);
        if (pre) { stageA(cur ^ 1, kt + 64); bload(kt + 64); }
        const unsigned short* Ac = As[cur];
        const unsigned short* Bc = Bs[cur];
#pragma unroll
        for (int kk = 0; kk < 2; ++kk) {
            bf16x8 af[4], bf[4];
#pragma unroll
            for (int i = 0; i < 4; ++i) {
                int ra = wm * 64 + i * 16 + rsel;
                af[i] = *(const bf16x8*)&Ac[ra * 64 + ((kk * 4 + csrcf) ^ (ra & 7)) * 8];
                int rb = wn * 64 + i * 16 + rsel;
                bf[i] = *(const bf16x8*)&Bc[rb * 64 + ((kk * 4 + csrcf) ^ (rb & 7)) * 8];
            }
#pragma unroll
            for (int i = 0; i < 4; ++i)
#pragma unroll
                for (int j = 0; j < 4; ++j)
                    acc[i][j] = __builtin_amdgcn_mfma_f32_16x16x32_bf16(af[i], bf[j], acc[i][j], 0, 0, 0);
        }
        if (pre) bwrite(cur ^ 1);
        cur ^= 1;
    }

    const int c = lane & 15, rbase = (lane >> 4) * 4;
    const int obase = offsets[e];
#pragma unroll
    for (int i = 0; i < 4; ++i) {
#pragma unroll
        for (int r = 0; r < 4; ++r) {
            int lrow = mtile * 128 + wm * 64 + i * 16 + rbase + r;
            if (lrow < cnt) {
                int grow = obase + lrow;
                int tok = row_tok[grow];
                float w = row_w[grow];
#pragma unroll
                for (int j = 0; j < 4; ++j) {
                    atomicAdd(&y[(size_t)tok * DIM + n0 + wn * 64 + j * 16 + c], w * acc[i][j][r]);
                }
            }
        }
    }
}

extern "C" void kernel_launch(void* const* d_in, const int* in_sizes, int n_in,
                              void* d_out, int out_size, void* d_ws, size_t ws_size,
                              hipStream_t stream) {
    const float* x  = (const float*)d_in[0];
    const float* rw = (const float*)d_in[1];
    const float* gw = (const float*)d_in[2];
    const float* uw = (const float*)d_in[3];
    const float* dw = (const float*)d_in[4];
    float* y = (float*)d_out;

    char* ws = (char*)d_ws;
    int*   counts  = (int*)(ws + 0);
    int*   cursors = (int*)(ws + 32);
    int*   offsets = (int*)(ws + 64);
    int*   top_idx = (int*)(ws + 128);
    float* top_w   = (float*)(ws + 128 + 16384);
    int*   row_tok = (int*)(ws + 128 + 32768);
    float* row_w   = (float*)(ws + 128 + 32768 + 16896);
    int*   tl_e    = (int*)(ws + 128 + 32768 + 2 * 16896);
    int*   tl_m    = (int*)(ws + 128 + 32768 + 2 * 16896 + 256);
    size_t off = 128 + 32768 + 2 * 16896 + 512;
    off = (off + 255) & ~(size_t)255;
    unsigned short* Abuf = (unsigned short*)(ws + off); off += (size_t)ROWS_PAD * DIM * 2;
    unsigned short* Hbuf = (unsigned short*)(ws + off); off += (size_t)ROWS_PAD * HDIM * 2;
    if (ws_size < off) return;  // workspace too small: fail loudly (zero output)

    hipMemsetAsync(counts, 0, 32, stream);
    hipMemsetAsync(d_out, 0, (size_t)out_size * 4, stream);

    router_kernel<<<T_TOK / 4, 256, 0, stream>>>(x, rw, counts, top_idx, top_w);
    scan_kernel<<<1, 64, 0, stream>>>(counts, offsets, cursors, tl_e, tl_m);
    gather_kernel<<<T_TOK, 256, 0, stream>>>(x, top_idx, top_w, cursors, row_tok, row_w, Abuf);

    gemm1_kernel<<<dim3(HDIM / 64, TSLOTS), 256, 0, stream>>>(Abuf, gw, uw, Hbuf,
                                                              offsets, counts, tl_e, tl_m);
    gemm2_kernel<<<dim3(DIM / 128, TSLOTS, 2), 256, 0, stream>>>(Hbuf, dw, y, offsets, counts,
                                                                 row_tok, row_w, tl_e, tl_m);
}